// Round 1
// baseline (231.771 us; speedup 1.0000x reference)
//
#include <hip/hip_runtime.h>

// EdgeLoss: mean |sobel_mag(gray(pred)) - sobel_mag(gray(target))|
// pred/target: (32, 3, 512, 512) fp32, output: scalar fp32.
// Memory-bound: 201 MB read once -> ~32 us floor at 6.3 TB/s.

#define BATCH 32
#define HH 512
#define WW 512
#define TX 64
#define TY 32
#define HALO_W (TX + 2)          // 66
#define HALO_H (TY + 2)          // 34
#define HALO_N (HALO_W * HALO_H) // 2244

__global__ void zero_out_kernel(float* out) { out[0] = 0.0f; }

__global__ __launch_bounds__(256) void edge_loss_kernel(
    const float* __restrict__ pred,
    const float* __restrict__ target,
    float* __restrict__ out)
{
    __shared__ float gp[HALO_N];
    __shared__ float gt[HALO_N];

    const int tid = threadIdx.x;
    const int x0 = blockIdx.x * TX;
    const int y0 = blockIdx.y * TY;
    const int b  = blockIdx.z;

    const size_t img = (size_t)HH * WW;
    const float* pbase = pred   + (size_t)b * 3 * img;
    const float* tbase = target + (size_t)b * 3 * img;

    // ---- Stage grayscale halo tile (66 x 34) for both images into LDS ----
    for (int idx = tid; idx < HALO_N; idx += 256) {
        const int ly = idx / HALO_W;
        const int lx = idx - ly * HALO_W;
        const int gy = y0 - 1 + ly;
        const int gx = x0 - 1 + lx;
        float vp = 0.0f, vt = 0.0f;
        if (gy >= 0 && gy < HH && gx >= 0 && gx < WW) {
            const int o = gy * WW + gx;
            vp = 0.299f * pbase[o] + 0.587f * pbase[o + img] + 0.114f * pbase[o + 2 * img];
            vt = 0.299f * tbase[o] + 0.587f * tbase[o + img] + 0.114f * tbase[o + 2 * img];
        }
        gp[idx] = vp;
        gt[idx] = vt;
    }
    __syncthreads();

    // ---- Compute: threads laid out 64 wide x 4 tall, each does 8 rows ----
    const int tx = tid & 63;
    const int ty = tid >> 6;  // 0..3 (constant within a wave)
    float lsum = 0.0f;

    #pragma unroll
    for (int i = 0; i < TY / 4; ++i) {
        const int ry = ty + 4 * i;                 // output row within tile
        const float* cp = &gp[ry * HALO_W + tx];   // top-left of 3x3 window
        const float* ct = &gt[ry * HALO_W + tx];

        float p00 = cp[0],          p01 = cp[1],              p02 = cp[2];
        float p10 = cp[HALO_W],                               p12 = cp[HALO_W + 2];
        float p20 = cp[2*HALO_W],   p21 = cp[2*HALO_W + 1],   p22 = cp[2*HALO_W + 2];
        float ex = (p02 - p00) + 2.0f * (p12 - p10) + (p22 - p20);
        float ey = (p20 - p00) + 2.0f * (p21 - p01) + (p22 - p02);
        float ep = sqrtf(ex * ex + ey * ey);

        float t00 = ct[0],          t01 = ct[1],              t02 = ct[2];
        float t10 = ct[HALO_W],                               t12 = ct[HALO_W + 2];
        float t20 = ct[2*HALO_W],   t21 = ct[2*HALO_W + 1],   t22 = ct[2*HALO_W + 2];
        float fx = (t02 - t00) + 2.0f * (t12 - t10) + (t22 - t20);
        float fy = (t20 - t00) + 2.0f * (t21 - t01) + (t22 - t02);
        float et = sqrtf(fx * fx + fy * fy);

        lsum += fabsf(ep - et);
    }

    // ---- Reduce: wave shuffle -> cross-wave LDS -> one atomic per block ----
    #pragma unroll
    for (int off = 32; off > 0; off >>= 1)
        lsum += __shfl_down(lsum, off, 64);

    __shared__ float wsum[4];
    if ((tid & 63) == 0) wsum[ty] = lsum;
    __syncthreads();
    if (tid == 0) {
        const float s = wsum[0] + wsum[1] + wsum[2] + wsum[3];
        const float inv_n = 1.0f / ((float)BATCH * HH * WW);
        atomicAdd(out, s * inv_n);
    }
}

extern "C" void kernel_launch(void* const* d_in, const int* in_sizes, int n_in,
                              void* d_out, int out_size, void* d_ws, size_t ws_size,
                              hipStream_t stream) {
    const float* pred   = (const float*)d_in[0];
    const float* target = (const float*)d_in[1];
    float* out = (float*)d_out;

    // d_out is poisoned 0xAA before every timed launch -> zero it on-stream.
    zero_out_kernel<<<1, 1, 0, stream>>>(out);

    dim3 grid(WW / TX, HH / TY, BATCH);  // (8, 16, 32) = 4096 blocks
    edge_loss_kernel<<<grid, 256, 0, stream>>>(pred, target, out);
}

// Round 2
// 224.719 us; speedup vs baseline: 1.0314x; 1.0314x over previous
//
#include <hip/hip_runtime.h>

// EdgeLoss: mean |sobel_mag(gray(pred)) - sobel_mag(gray(target))|
// pred/target: (32, 3, 512, 512) fp32, output: scalar fp32.
// Memory-bound: 201 MB read once -> ~32 us floor at 6.3 TB/s.
//
// R1 -> R2: staging was scalar 4B loads, compiler squeezed to 12 VGPRs ->
// dependent load chain -> 2.2 TB/s. Now: float4 staging from x0-4 (72 floats
// per halo row; every float4 fully in- or out-of-bounds since x0 % 64 == 0),
// 3 unrolled trips x 6 independent float4 loads.

#define BATCH 32
#define HH 512
#define WW 512
#define TX 64
#define TY 32
#define LDS_W 72                  // floats per staged row (x0-4 .. x0+67)
#define LDS_W4 18                 // float4 per staged row
#define LDS_ROWS 34               // y0-1 .. y0+32
#define SLOTS (LDS_ROWS * LDS_W4) // 612 float4 slots per image

__global__ void zero_out_kernel(float* out) { out[0] = 0.0f; }

__global__ __launch_bounds__(256) void edge_loss_kernel(
    const float* __restrict__ pred,
    const float* __restrict__ target,
    float* __restrict__ out)
{
    __shared__ float gp[LDS_ROWS * LDS_W];
    __shared__ float gt[LDS_ROWS * LDS_W];

    const int tid = threadIdx.x;
    const int x0 = blockIdx.x * TX;
    const int y0 = blockIdx.y * TY;
    const int b  = blockIdx.z;

    const size_t img = (size_t)HH * WW;
    const float* pbase = pred   + (size_t)b * 3 * img;
    const float* tbase = target + (size_t)b * 3 * img;

    float4* gp4 = (float4*)gp;
    float4* gt4 = (float4*)gt;

    // ---- Stage grayscale halo tile (72 x 34) for both images, float4 ----
    #pragma unroll
    for (int t = 0; t < 3; ++t) {
        const int i = tid + t * 256;
        if (i < SLOTS) {
            const int row = i / LDS_W4;          // 0..33
            const int c   = i - row * LDS_W4;    // 0..17
            const int gy = y0 - 1 + row;
            const int gx = x0 - 4 + 4 * c;
            float4 vp = make_float4(0.f, 0.f, 0.f, 0.f);
            float4 vt = make_float4(0.f, 0.f, 0.f, 0.f);
            if (gy >= 0 && gy < HH && gx >= 0 && gx <= WW - 4) {
                const size_t o = (size_t)gy * WW + gx;
                const float4 pr = *(const float4*)(pbase + o);
                const float4 pg = *(const float4*)(pbase + o + img);
                const float4 pb = *(const float4*)(pbase + o + 2 * img);
                const float4 tr = *(const float4*)(tbase + o);
                const float4 tg = *(const float4*)(tbase + o + img);
                const float4 tb = *(const float4*)(tbase + o + 2 * img);
                vp.x = 0.299f * pr.x + 0.587f * pg.x + 0.114f * pb.x;
                vp.y = 0.299f * pr.y + 0.587f * pg.y + 0.114f * pb.y;
                vp.z = 0.299f * pr.z + 0.587f * pg.z + 0.114f * pb.z;
                vp.w = 0.299f * pr.w + 0.587f * pg.w + 0.114f * pb.w;
                vt.x = 0.299f * tr.x + 0.587f * tg.x + 0.114f * tb.x;
                vt.y = 0.299f * tr.y + 0.587f * tg.y + 0.114f * tb.y;
                vt.z = 0.299f * tr.z + 0.587f * tg.z + 0.114f * tb.z;
                vt.w = 0.299f * tr.w + 0.587f * tg.w + 0.114f * tb.w;
            }
            gp4[i] = vp;
            gt4[i] = vt;
        }
    }
    __syncthreads();

    // ---- Compute: 64 wide x 4 tall, each thread does 8 rows ----
    const int tx = tid & 63;
    const int ty = tid >> 6;
    float lsum = 0.0f;

    #pragma unroll
    for (int i = 0; i < TY / 4; ++i) {
        const int ry = ty + 4 * i;                     // output row within tile
        const float* cp = &gp[ry * LDS_W + tx + 3];    // window top-left
        const float* ct = &gt[ry * LDS_W + tx + 3];

        float p00 = cp[0],         p01 = cp[1],             p02 = cp[2];
        float p10 = cp[LDS_W],                              p12 = cp[LDS_W + 2];
        float p20 = cp[2*LDS_W],   p21 = cp[2*LDS_W + 1],   p22 = cp[2*LDS_W + 2];
        float ex = (p02 - p00) + 2.0f * (p12 - p10) + (p22 - p20);
        float ey = (p20 - p00) + 2.0f * (p21 - p01) + (p22 - p02);
        float ep = sqrtf(ex * ex + ey * ey);

        float t00 = ct[0],         t01 = ct[1],             t02 = ct[2];
        float t10 = ct[LDS_W],                              t12 = ct[LDS_W + 2];
        float t20 = ct[2*LDS_W],   t21 = ct[2*LDS_W + 1],   t22 = ct[2*LDS_W + 2];
        float fx = (t02 - t00) + 2.0f * (t12 - t10) + (t22 - t20);
        float fy = (t20 - t00) + 2.0f * (t21 - t01) + (t22 - t02);
        float et = sqrtf(fx * fx + fy * fy);

        lsum += fabsf(ep - et);
    }

    // ---- Reduce: wave shuffle -> cross-wave LDS -> one atomic per block ----
    #pragma unroll
    for (int off = 32; off > 0; off >>= 1)
        lsum += __shfl_down(lsum, off, 64);

    __shared__ float wsum[4];
    if ((tid & 63) == 0) wsum[ty] = lsum;
    __syncthreads();
    if (tid == 0) {
        const float s = wsum[0] + wsum[1] + wsum[2] + wsum[3];
        const float inv_n = 1.0f / ((float)BATCH * HH * WW);
        atomicAdd(out, s * inv_n);
    }
}

extern "C" void kernel_launch(void* const* d_in, const int* in_sizes, int n_in,
                              void* d_out, int out_size, void* d_ws, size_t ws_size,
                              hipStream_t stream) {
    const float* pred   = (const float*)d_in[0];
    const float* target = (const float*)d_in[1];
    float* out = (float*)d_out;

    // d_out is poisoned 0xAA before every timed launch -> zero it on-stream.
    zero_out_kernel<<<1, 1, 0, stream>>>(out);

    dim3 grid(WW / TX, HH / TY, BATCH);  // (8, 16, 32) = 4096 blocks
    edge_loss_kernel<<<grid, 256, 0, stream>>>(pred, target, out);
}